// Round 1
// baseline (864.205 us; speedup 1.0000x reference)
//
#include <hip/hip_runtime.h>
#include <cstddef>

// Shapes: B=8, NWIN=256, NTOK=64, DIM=192, HEADS=6, d=32, 3C=576
// R = B*NWIN*NTOK = 131072 rows.
//
// ws layout (floats):
//   vT     [1536][16384]  : v transposed to [(b*192+h*32+dd)][win*64+tok]   25165824
//   attbuf [1536][16384]  : pre-proj out  [(b*192+h*32+dd)][i*64+tok]       25165824
//   qg     [1536][256]    : grad magnitude of scaled q, [(b*192+hd)][win]     393216
//   kg     [1536][256]                                                        393216
// total 51118080 floats = 204.5 MB

#define SCALE 0.17677669529663687f   // 1/sqrt(32)

// ---------------- Kernel A: QKV GEMM + grad-magnitude epilogue ----------------
// grid (9, 2048), block 256. M-tile = 64 rows = exactly one window.
__global__ __launch_bounds__(256) void qkv_grad_kernel(
    const float* __restrict__ x, const float* __restrict__ w,
    const float* __restrict__ bias, float* __restrict__ vT,
    float* __restrict__ qg, float* __restrict__ kg)
{
    __shared__ float As[16][68];
    __shared__ float Ws[16][68];
    __shared__ float Ts[64][66];   // q/k tile for grad reduction

    const int tid = threadIdx.x;
    const int tile_m = blockIdx.y;       // 0..2047  (global window index)
    const int c0 = blockIdx.x * 64;      // 0..512
    const int m0 = tile_m * 64;
    const int ty = tid & 15, tx = tid >> 4;
    const int lm = tid >> 2;             // 0..63
    const int lk4 = (tid & 3) * 4;       // {0,4,8,12}

    float acc[4][4] = {};

    const float* xp = x + (size_t)(m0 + lm) * 192 + lk4;
    const float* wp = w + (size_t)(c0 + lm) * 192 + lk4;

    for (int k0 = 0; k0 < 192; k0 += 16) {
        float4 a4 = *(const float4*)(xp + k0);
        float4 w4 = *(const float4*)(wp + k0);
        __syncthreads();
        As[lk4+0][lm] = a4.x; As[lk4+1][lm] = a4.y;
        As[lk4+2][lm] = a4.z; As[lk4+3][lm] = a4.w;
        Ws[lk4+0][lm] = w4.x; Ws[lk4+1][lm] = w4.y;
        Ws[lk4+2][lm] = w4.z; Ws[lk4+3][lm] = w4.w;
        __syncthreads();
#pragma unroll
        for (int kk = 0; kk < 16; ++kk) {
            float4 av = *(const float4*)&As[kk][ty*4];
            float4 bv = *(const float4*)&Ws[kk][tx*4];
            float a_[4] = {av.x, av.y, av.z, av.w};
            float b_[4] = {bv.x, bv.y, bv.z, bv.w};
#pragma unroll
            for (int i = 0; i < 4; ++i)
#pragma unroll
                for (int j = 0; j < 4; ++j)
                    acc[i][j] = fmaf(a_[i], b_[j], acc[i][j]);
        }
    }
#pragma unroll
    for (int j = 0; j < 4; ++j) {
        float bj = bias[c0 + tx*4 + j];
#pragma unroll
        for (int i = 0; i < 4; ++i) acc[i][j] += bj;
    }

    const int which = c0 / 192;          // 0:q 1:k 2:v (tile never straddles)
    const int b = tile_m >> 8;
    const int win = tile_m & 255;

    if (which == 2) {
        const int hd0 = c0 - 384;
#pragma unroll
        for (int j = 0; j < 4; ++j) {
            float4 v4 = make_float4(acc[0][j], acc[1][j], acc[2][j], acc[3][j]);
            *(float4*)(vT + (size_t)(b*192 + hd0 + tx*4 + j)*16384 + win*64 + ty*4) = v4;
        }
    } else {
        __syncthreads();
#pragma unroll
        for (int i = 0; i < 4; ++i)
#pragma unroll
            for (int j = 0; j < 4; ++j)
                Ts[ty*4 + i][tx*4 + j] = acc[i][j];
        __syncthreads();
        if (tid < 64) {
            // token t = y*8+x; gx along x (zero pre-pad), gy along y
            float sum = 0.f;
#pragma unroll
            for (int t = 0; t < 64; ++t) {
                float v  = Ts[t][tid];
                float gx = v - ((t & 7)  ? Ts[t-1][tid] : 0.f);
                float gy = v - ((t >= 8) ? Ts[t-8][tid] : 0.f);
                sum += fabsf(gx) + fabsf(gy);
            }
            const int hd = (c0 + tid) % 192;
            float* dst = (which == 0) ? qg : kg;
            const float s = (which == 0) ? SCALE : 1.0f;
            dst[(size_t)(b*192 + hd)*256 + win] = sum * s;
        }
    }
}

// ---------------- Kernel B: rank-1-score softmax attention ----------------
// grid 1536 (one block per (b,h,dd)), block 256 (one thread per query window i).
__global__ __launch_bounds__(256) void attn_kernel(
    const float* __restrict__ vT, const float* __restrict__ qg,
    const float* __restrict__ kg, float* __restrict__ attbuf)
{
    __shared__ float Vs[4096];     // 64 windows x 64 tokens chunk
    __shared__ float kds[256];
    __shared__ float red[256];

    const int g = blockIdx.x;
    const int tid = threadIdx.x;

    float kv = kg[(size_t)g*256 + tid];
    red[tid] = kv;
    __syncthreads();
    for (int s = 128; s > 0; s >>= 1) {
        if (tid < s) red[tid] = fmaxf(red[tid], red[tid + s]);
        __syncthreads();
    }
    const float kmax = red[0];
    kds[tid] = kv - kmax;          // <= 0
    const float ai = qg[(size_t)g*256 + tid];   // >= 0

    float4 acc[16];
#pragma unroll
    for (int t = 0; t < 16; ++t) acc[t] = make_float4(0.f, 0.f, 0.f, 0.f);
    float den = 0.f;

    const float* vbase = vT + (size_t)g * 16384;
    for (int c = 0; c < 4; ++c) {
        __syncthreads();           // also makes kds visible on first pass
#pragma unroll
        for (int u = 0; u < 4; ++u) {
            int f = tid*4 + u*1024;
            *(float4*)&Vs[f] = *(const float4*)(vbase + c*4096 + f);
        }
        __syncthreads();
        for (int j = 0; j < 64; ++j) {
            float e = __expf(ai * kds[c*64 + j]);
            den += e;
            const float* vr = &Vs[j*64];
#pragma unroll
            for (int t = 0; t < 16; ++t) {
                float4 v4 = *(const float4*)(vr + t*4);
                acc[t].x = fmaf(e, v4.x, acc[t].x);
                acc[t].y = fmaf(e, v4.y, acc[t].y);
                acc[t].z = fmaf(e, v4.z, acc[t].z);
                acc[t].w = fmaf(e, v4.w, acc[t].w);
            }
        }
    }
    const float inv = 1.0f / den;  // den >= 1 (j=argmax term is exp(0)=1 when ai>0; 256 when ai==0)
    float* ob = attbuf + (size_t)g*16384 + (size_t)tid*64;
#pragma unroll
    for (int t = 0; t < 16; ++t) {
        float4 o = make_float4(acc[t].x*inv, acc[t].y*inv, acc[t].z*inv, acc[t].w*inv);
        *(float4*)(ob + t*4) = o;
    }
}

// ---------------- Kernel C: proj GEMM ----------------
// grid (3, 2048), block 256. A read from attbuf (per-b column-major over k).
__global__ __launch_bounds__(256) void proj_kernel(
    const float* __restrict__ attbuf, const float* __restrict__ w,
    const float* __restrict__ bias, float* __restrict__ out)
{
    __shared__ float As[16][68];
    __shared__ float Ws[16][68];

    const int tid = threadIdx.x;
    const int tile_m = blockIdx.y;       // 0..2047
    const int c0 = blockIdx.x * 64;      // 0..128
    const int ty = tid & 15, tx = tid >> 4;
    const int b = tile_m >> 8;
    const int mm0 = (tile_m & 255) * 64;
    const int lane = tid & 63, kbase = tid >> 6;  // kk = kbase + 4*j
    const int lm = tid >> 2;
    const int lk4 = (tid & 3) * 4;

    const float* Ab = attbuf + (size_t)b * 3145728 + mm0;   // 192*16384
    const float* wp = w + (size_t)(c0 + lm) * 192 + lk4;

    float acc[4][4] = {};

    for (int k0 = 0; k0 < 192; k0 += 16) {
        float a[4];
#pragma unroll
        for (int j = 0; j < 4; ++j)
            a[j] = Ab[(size_t)(k0 + kbase + j*4) * 16384 + lane];
        float4 w4 = *(const float4*)(wp + k0);
        __syncthreads();
#pragma unroll
        for (int j = 0; j < 4; ++j) As[kbase + j*4][lane] = a[j];
        Ws[lk4+0][lm] = w4.x; Ws[lk4+1][lm] = w4.y;
        Ws[lk4+2][lm] = w4.z; Ws[lk4+3][lm] = w4.w;
        __syncthreads();
#pragma unroll
        for (int kk = 0; kk < 16; ++kk) {
            float4 av = *(const float4*)&As[kk][ty*4];
            float4 bv = *(const float4*)&Ws[kk][tx*4];
            float a_[4] = {av.x, av.y, av.z, av.w};
            float b_[4] = {bv.x, bv.y, bv.z, bv.w};
#pragma unroll
            for (int i = 0; i < 4; ++i)
#pragma unroll
                for (int j = 0; j < 4; ++j)
                    acc[i][j] = fmaf(a_[i], b_[j], acc[i][j]);
        }
    }

    const int m0 = tile_m * 64;
#pragma unroll
    for (int i = 0; i < 4; ++i) {
        float4 o;
        o.x = acc[i][0] + bias[c0 + tx*4 + 0];
        o.y = acc[i][1] + bias[c0 + tx*4 + 1];
        o.z = acc[i][2] + bias[c0 + tx*4 + 2];
        o.w = acc[i][3] + bias[c0 + tx*4 + 3];
        *(float4*)(out + (size_t)(m0 + ty*4 + i)*192 + c0 + tx*4) = o;
    }
}

extern "C" void kernel_launch(void* const* d_in, const int* in_sizes, int n_in,
                              void* d_out, int out_size, void* d_ws, size_t ws_size,
                              hipStream_t stream) {
    const float* x      = (const float*)d_in[0];
    const float* qkv_w  = (const float*)d_in[1];
    const float* qkv_b  = (const float*)d_in[2];
    const float* proj_w = (const float*)d_in[3];
    const float* proj_b = (const float*)d_in[4];
    float* out = (float*)d_out;

    float* vT     = (float*)d_ws;
    float* attbuf = vT + 25165824;
    float* qg     = attbuf + 25165824;
    float* kg     = qg + 393216;

    qkv_grad_kernel<<<dim3(9, 2048), 256, 0, stream>>>(x, qkv_w, qkv_b, vT, qg, kg);
    attn_kernel<<<dim3(1536), 256, 0, stream>>>(vT, qg, kg, attbuf);
    proj_kernel<<<dim3(3, 2048), 256, 0, stream>>>(attbuf, proj_w, proj_b, out);
}

// Round 2
// 748.462 us; speedup vs baseline: 1.1546x; 1.1546x over previous
//
#include <hip/hip_runtime.h>
#include <cstddef>

// Shapes: B=8, NWIN=256, NTOK=64, DIM=192, HEADS=6, d=32, 3C=576
// R = B*NWIN*NTOK = 131072 rows.
//
// ws layout:
//   vT16   [1536][16384] bf16 : v transposed [(b*192+h*32+dd)][win*64+tok]  (50.3 MB)
//   attbuf [1536][16384] f32  : pre-proj out; ALIASED before attn as x_hi/x_lo bf16
//   qg,kg  [1536][256]   f32
//   Bp     [576][576]    bf16 : B' = [w_hi ; w_lo ; w_hi] along K (tripled-K split GEMM)

#define SCALE 0.17677669529663687f   // 1/sqrt(32)

typedef __attribute__((ext_vector_type(8))) short short8;
typedef __attribute__((ext_vector_type(4))) float f32x4;

__device__ __forceinline__ unsigned short f2bf(float f) {
    unsigned u = __float_as_uint(f);
    u += 0x7fffu + ((u >> 16) & 1u);
    return (unsigned short)(u >> 16);
}
__device__ __forceinline__ float bf2f(unsigned int h) {
    return __uint_as_float(h << 16);
}
__device__ __forceinline__ void gl2lds16(const void* g, void* l) {
    __builtin_amdgcn_global_load_lds(
        (const __attribute__((address_space(1))) void*)g,
        (__attribute__((address_space(3))) void*)l, 16, 0, 0);
}

// ---------------- split x into bf16 hi/lo ----------------
__global__ __launch_bounds__(256) void split_kernel(
    const float* __restrict__ x, unsigned short* __restrict__ xh,
    unsigned short* __restrict__ xl)
{
    size_t base = ((size_t)blockIdx.x * 256 + threadIdx.x) * 8;
    float4 a = *(const float4*)(x + base);
    float4 b = *(const float4*)(x + base + 4);
    float v[8] = {a.x, a.y, a.z, a.w, b.x, b.y, b.z, b.w};
    unsigned short h[8], l[8];
#pragma unroll
    for (int i = 0; i < 8; ++i) {
        h[i] = f2bf(v[i]);
        l[i] = f2bf(v[i] - bf2f(h[i]));
    }
    *(ushort4*)(xh + base)     = make_ushort4(h[0], h[1], h[2], h[3]);
    *(ushort4*)(xh + base + 4) = make_ushort4(h[4], h[5], h[6], h[7]);
    *(ushort4*)(xl + base)     = make_ushort4(l[0], l[1], l[2], l[3]);
    *(ushort4*)(xl + base + 4) = make_ushort4(l[4], l[5], l[6], l[7]);
}

// ---------------- build B' [576 N][576 K] = [w_hi ; w_lo ; w_hi] ----------------
__global__ __launch_bounds__(256) void bsplit_kernel(
    const float* __restrict__ w, unsigned short* __restrict__ Bp)
{
    int idx = blockIdx.x * 256 + threadIdx.x;   // < 331776 = 1296*256
    int n = idx / 576, k = idx % 576;
    float v = w[n * 192 + (k % 192)];
    unsigned short h = f2bf(v);
    Bp[idx] = (k >= 192 && k < 384) ? f2bf(v - bf2f(h)) : h;
}

// ---------------- Kernel A: split-bf16 MFMA QKV GEMM + grad epilogue ----------------
// grid (9, 512), block 256 = 4 waves. Block tile M=256 (4 windows, wave w owns
// window w as a 64x64 wave tile), N=64, K=576 (tripled), BK=32.
__global__ __launch_bounds__(256) void qkv_mfma_kernel(
    const unsigned short* __restrict__ x_hi, const unsigned short* __restrict__ x_lo,
    const unsigned short* __restrict__ Bp, const float* __restrict__ bias,
    unsigned short* __restrict__ vT, float* __restrict__ qg, float* __restrict__ kg)
{
    __shared__ unsigned short As[256 * 32];   // [row 256][k 32]
    __shared__ unsigned short Bs[64 * 32];    // [n 64][k 32]

    const int tid  = threadIdx.x;
    const int wave = tid >> 6, lane = tid & 63;
    const int quad = lane >> 4, col = lane & 15;
    const int c0 = blockIdx.x * 64;          // N offset (never straddles q/k/v)
    const int m0 = blockIdx.y * 256;

    f32x4 acc[4][4];
#pragma unroll
    for (int mi = 0; mi < 4; ++mi)
#pragma unroll
        for (int ni = 0; ni < 4; ++ni) {
            f32x4 z = {0.f, 0.f, 0.f, 0.f};
            acc[mi][ni] = z;
        }

    const int lr = lane >> 2;            // 0..15: row-within-16 for staging
    const int lk = (lane & 3) * 8;       // k element offset for staging

    for (int kk = 0; kk < 18; ++kk) {
        // K segment: kk<12 -> x_hi (k mod 192), kk>=12 -> x_lo
        const unsigned short* Asrc = (kk < 12) ? x_hi : x_lo;
        const int ksrc = (kk % 6) * 32;
        __syncthreads();
#pragma unroll
        for (int s = 0; s < 5; ++s) {
            int c = wave * 5 + s;        // 20 one-KB staging calls
            if (c < 16) {
                int row = c * 16 + lr;
                const unsigned short* g = Asrc + (size_t)(m0 + row) * 192 + ksrc + lk;
                gl2lds16(g, &As[c * 512]);
            } else {
                int cb = c - 16;
                int row = cb * 16 + lr;
                const unsigned short* g = Bp + (size_t)(c0 + row) * 576 + kk * 32 + lk;
                gl2lds16(g, &Bs[cb * 512]);
            }
        }
        __syncthreads();

        short8 af[4], bfr[4];
#pragma unroll
        for (int mi = 0; mi < 4; ++mi)
            af[mi] = *(const short8*)&As[(wave * 64 + mi * 16 + col) * 32 + quad * 8];
#pragma unroll
        for (int ni = 0; ni < 4; ++ni)
            bfr[ni] = *(const short8*)&Bs[(ni * 16 + col) * 32 + quad * 8];
#pragma unroll
        for (int mi = 0; mi < 4; ++mi)
#pragma unroll
            for (int ni = 0; ni < 4; ++ni)
                acc[mi][ni] = __builtin_amdgcn_mfma_f32_16x16x32_bf16(
                    af[mi], bfr[ni], acc[mi][ni], 0, 0, 0);
    }

    // bias (must precede grads: zero-pad boundary terms keep the bias)
#pragma unroll
    for (int ni = 0; ni < 4; ++ni) {
        float bv = bias[c0 + ni * 16 + col];
#pragma unroll
        for (int mi = 0; mi < 4; ++mi)
#pragma unroll
            for (int r = 0; r < 4; ++r)
                acc[mi][ni][r] += bv;
    }

    const int gw = blockIdx.y * 4 + wave;    // global window of this wave
    const int b = gw >> 8, win = gw & 255;
    const int which = c0 / 192;              // 0:q 1:k 2:v

    if (which == 2) {
        const int hd0 = c0 - 384;
#pragma unroll
        for (int mi = 0; mi < 4; ++mi)
#pragma unroll
            for (int ni = 0; ni < 4; ++ni) {
                int tok0 = mi * 16 + quad * 4;       // C layout: row = quad*4+r
                int ch = hd0 + ni * 16 + col;        //           col = lane&15
                ushort4 o = make_ushort4(f2bf(acc[mi][ni][0]), f2bf(acc[mi][ni][1]),
                                         f2bf(acc[mi][ni][2]), f2bf(acc[mi][ni][3]));
                *(ushort4*)(vT + (size_t)(b * 192 + ch) * 16384 + win * 64 + tok0) = o;
            }
    } else {
        float* dst = (which == 0) ? qg : kg;
        const float sc = (which == 0) ? SCALE : 1.0f;
        const int hdb = (which == 0) ? c0 : c0 - 192;
        // token t = mi*16 + quad*4 + r; channel = ni*16 + col.
        // gx needs t-1 (reg-1, or quad-1's r=3 via shfl_xor 16; t&7==0 -> zero pad)
        // gy needs t-8 (quad^2 via shfl_xor 32, mi-1 when quad<2; t<8 -> zero pad)
#pragma unroll
        for (int ni = 0; ni < 4; ++ni) {
            float yx[4][4], p3[4];
#pragma unroll
            for (int mi = 0; mi < 4; ++mi) {
#pragma unroll
                for (int r = 0; r < 4; ++r)
                    yx[mi][r] = __shfl_xor(acc[mi][ni][r], 32);
                p3[mi] = __shfl_xor(acc[mi][ni][3], 16);
            }
            float s = 0.f;
#pragma unroll
            for (int mi = 0; mi < 4; ++mi)
#pragma unroll
                for (int r = 0; r < 4; ++r) {
                    float v = acc[mi][ni][r];
                    float gx = (r > 0) ? (v - acc[mi][ni][r - 1])
                                       : ((quad & 1) ? (v - p3[mi]) : v);
                    float gy = (quad >= 2) ? (v - yx[mi][r])
                                           : ((mi > 0) ? (v - yx[mi - 1][r]) : v);
                    s += fabsf(gx) + fabsf(gy);
                }
            s += __shfl_xor(s, 16);
            s += __shfl_xor(s, 32);
            if (lane < 16)
                dst[(size_t)(b * 192 + hdb + ni * 16 + lane) * 256 + win] = s * sc;
        }
    }
}

// ---------------- Kernel B: rank-1-score softmax attention (bf16 V) ----------------
__global__ __launch_bounds__(256) void attn_kernel(
    const unsigned short* __restrict__ vT, const float* __restrict__ qg,
    const float* __restrict__ kg, float* __restrict__ attbuf)
{
    __shared__ float Vs[4096];     // 64 windows x 64 tokens chunk
    __shared__ float kds[256];
    __shared__ float red[256];

    const int g = blockIdx.x;
    const int tid = threadIdx.x;

    float kv = kg[(size_t)g * 256 + tid];
    red[tid] = kv;
    __syncthreads();
    for (int s = 128; s > 0; s >>= 1) {
        if (tid < s) red[tid] = fmaxf(red[tid], red[tid + s]);
        __syncthreads();
    }
    const float kmax = red[0];
    kds[tid] = kv - kmax;                       // <= 0
    const float ai = qg[(size_t)g * 256 + tid]; // >= 0

    float4 acc[16];
#pragma unroll
    for (int t = 0; t < 16; ++t) acc[t] = make_float4(0.f, 0.f, 0.f, 0.f);
    float den = 0.f;

    const unsigned short* vbase = vT + (size_t)g * 16384;
    for (int c = 0; c < 4; ++c) {
        __syncthreads();           // also makes kds visible on first pass
        const uint4* src = (const uint4*)(vbase + c * 4096);
#pragma unroll
        for (int u = 0; u < 2; ++u) {
            uint4 q4 = src[tid * 2 + u];
            float* d = &Vs[tid * 16 + u * 8];
            d[0] = bf2f(q4.x & 0xffffu); d[1] = bf2f(q4.x >> 16);
            d[2] = bf2f(q4.y & 0xffffu); d[3] = bf2f(q4.y >> 16);
            d[4] = bf2f(q4.z & 0xffffu); d[5] = bf2f(q4.z >> 16);
            d[6] = bf2f(q4.w & 0xffffu); d[7] = bf2f(q4.w >> 16);
        }
        __syncthreads();
        for (int j = 0; j < 64; ++j) {
            float e = __expf(ai * kds[c * 64 + j]);
            den += e;
            const float* vr = &Vs[j * 64];
#pragma unroll
            for (int t = 0; t < 16; ++t) {
                float4 v4 = *(const float4*)(vr + t * 4);
                acc[t].x = fmaf(e, v4.x, acc[t].x);
                acc[t].y = fmaf(e, v4.y, acc[t].y);
                acc[t].z = fmaf(e, v4.z, acc[t].z);
                acc[t].w = fmaf(e, v4.w, acc[t].w);
            }
        }
    }
    const float inv = 1.0f / den;
    float* ob = attbuf + (size_t)g * 16384 + (size_t)tid * 64;
#pragma unroll
    for (int t = 0; t < 16; ++t) {
        float4 o = make_float4(acc[t].x * inv, acc[t].y * inv, acc[t].z * inv, acc[t].w * inv);
        *(float4*)(ob + t * 4) = o;
    }
}

// ---------------- Kernel C: proj GEMM ----------------
__global__ __launch_bounds__(256) void proj_kernel(
    const float* __restrict__ attbuf, const float* __restrict__ w,
    const float* __restrict__ bias, float* __restrict__ out)
{
    __shared__ float As[16][68];
    __shared__ float Ws[16][68];

    const int tid = threadIdx.x;
    const int tile_m = blockIdx.y;       // 0..2047
    const int c0 = blockIdx.x * 64;      // 0..128
    const int ty = tid & 15, tx = tid >> 4;
    const int b = tile_m >> 8;
    const int mm0 = (tile_m & 255) * 64;
    const int lane = tid & 63, kbase = tid >> 6;
    const int lm = tid >> 2;
    const int lk4 = (tid & 3) * 4;

    const float* Ab = attbuf + (size_t)b * 3145728 + mm0;   // 192*16384
    const float* wp = w + (size_t)(c0 + lm) * 192 + lk4;

    float acc[4][4] = {};

    for (int k0 = 0; k0 < 192; k0 += 16) {
        float a[4];
#pragma unroll
        for (int j = 0; j < 4; ++j)
            a[j] = Ab[(size_t)(k0 + kbase + j * 4) * 16384 + lane];
        float4 w4 = *(const float4*)(wp + k0);
        __syncthreads();
#pragma unroll
        for (int j = 0; j < 4; ++j) As[kbase + j * 4][lane] = a[j];
        Ws[lk4 + 0][lm] = w4.x; Ws[lk4 + 1][lm] = w4.y;
        Ws[lk4 + 2][lm] = w4.z; Ws[lk4 + 3][lm] = w4.w;
        __syncthreads();
#pragma unroll
        for (int kk = 0; kk < 16; ++kk) {
            float4 av = *(const float4*)&As[kk][ty * 4];
            float4 bv = *(const float4*)&Ws[kk][tx * 4];
            float a_[4] = {av.x, av.y, av.z, av.w};
            float b_[4] = {bv.x, bv.y, bv.z, bv.w};
#pragma unroll
            for (int i = 0; i < 4; ++i)
#pragma unroll
                for (int j = 0; j < 4; ++j)
                    acc[i][j] = fmaf(a_[i], b_[j], acc[i][j]);
        }
    }

    const int m0 = tile_m * 64;
#pragma unroll
    for (int i = 0; i < 4; ++i) {
        float4 o;
        o.x = acc[i][0] + bias[c0 + tx * 4 + 0];
        o.y = acc[i][1] + bias[c0 + tx * 4 + 1];
        o.z = acc[i][2] + bias[c0 + tx * 4 + 2];
        o.w = acc[i][3] + bias[c0 + tx * 4 + 3];
        *(float4*)(out + (size_t)(m0 + ty * 4 + i) * 192 + c0 + tx * 4) = o;
    }
}

extern "C" void kernel_launch(void* const* d_in, const int* in_sizes, int n_in,
                              void* d_out, int out_size, void* d_ws, size_t ws_size,
                              hipStream_t stream) {
    const float* x      = (const float*)d_in[0];
    const float* qkv_w  = (const float*)d_in[1];
    const float* qkv_b  = (const float*)d_in[2];
    const float* proj_w = (const float*)d_in[3];
    const float* proj_b = (const float*)d_in[4];
    float* out = (float*)d_out;

    float* wsf = (float*)d_ws;
    unsigned short* vT16 = (unsigned short*)wsf;          // 25165824 bf16
    float* attbuf = wsf + 12582912;                       // 25165824 f32
    unsigned short* x_hi = (unsigned short*)attbuf;       // aliases attbuf (dead by then)
    unsigned short* x_lo = x_hi + 25165824;
    float* qg = attbuf + 25165824;                        // 393216 f32
    float* kg = qg + 393216;
    unsigned short* Bp = (unsigned short*)(kg + 393216);  // 331776 bf16

    split_kernel<<<12288, 256, 0, stream>>>(x, x_hi, x_lo);
    bsplit_kernel<<<1296, 256, 0, stream>>>(qkv_w, Bp);
    qkv_mfma_kernel<<<dim3(9, 512), 256, 0, stream>>>(x_hi, x_lo, Bp, qkv_b, vT16, qg, kg);
    attn_kernel<<<dim3(1536), 256, 0, stream>>>(vT16, qg, kg, attbuf);
    proj_kernel<<<dim3(3, 2048), 256, 0, stream>>>(attbuf, proj_w, proj_b, out);
}

// Round 3
// 475.338 us; speedup vs baseline: 1.8181x; 1.5746x over previous
//
#include <hip/hip_runtime.h>
#include <cstddef>

// Shapes: B=8, NWIN=256, NTOK=64, DIM=192, HEADS=6, d=32, 3C=576
// ws layout (u16 units from base):
//   vT16    [0,        25165824)  bf16 v transposed [(b*192+ch)][win*64+tok]
//   x_hi    [25165824, 50331648)  bf16   } attbuf16 ALIASES x_hi (dead after qkv)
//   x_lo    [50331648, 75497472)  bf16
//   qg,kg   f32 at u16 offset 75497472 (2 x 393216 f32)
//   Bp      [576][576] bf16 (qkv split weights), Wp [192][192] bf16 (proj weights)

#define SCALE 0.17677669529663687f   // 1/sqrt(32)

typedef __attribute__((ext_vector_type(8))) short short8;
typedef __attribute__((ext_vector_type(4))) float f32x4;

__device__ __forceinline__ unsigned short f2bf(float f) {
    unsigned u = __float_as_uint(f);
    u += 0x7fffu + ((u >> 16) & 1u);
    return (unsigned short)(u >> 16);
}
__device__ __forceinline__ float bf2f(unsigned int h) {
    return __uint_as_float(h << 16);
}
__device__ __forceinline__ void gl2lds16(const void* g, void* l) {
    __builtin_amdgcn_global_load_lds(
        (const __attribute__((address_space(1))) void*)g,
        (__attribute__((address_space(3))) void*)l, 16, 0, 0);
}

// ---------------- split x into bf16 hi/lo ----------------
__global__ __launch_bounds__(256) void split_kernel(
    const float* __restrict__ x, unsigned short* __restrict__ xh,
    unsigned short* __restrict__ xl)
{
    size_t base = ((size_t)blockIdx.x * 256 + threadIdx.x) * 8;
    float4 a = *(const float4*)(x + base);
    float4 b = *(const float4*)(x + base + 4);
    float v[8] = {a.x, a.y, a.z, a.w, b.x, b.y, b.z, b.w};
    unsigned short h[8], l[8];
#pragma unroll
    for (int i = 0; i < 8; ++i) {
        h[i] = f2bf(v[i]);
        l[i] = f2bf(v[i] - bf2f(h[i]));
    }
    *(ushort4*)(xh + base)     = make_ushort4(h[0], h[1], h[2], h[3]);
    *(ushort4*)(xh + base + 4) = make_ushort4(h[4], h[5], h[6], h[7]);
    *(ushort4*)(xl + base)     = make_ushort4(l[0], l[1], l[2], l[3]);
    *(ushort4*)(xl + base + 4) = make_ushort4(l[4], l[5], l[6], l[7]);
}

// ---------------- build B' [576 N][576 K] = [w_hi ; w_lo ; w_hi] ----------------
__global__ __launch_bounds__(256) void bsplit_kernel(
    const float* __restrict__ w, unsigned short* __restrict__ Bp)
{
    int idx = blockIdx.x * 256 + threadIdx.x;   // < 331776
    int k = idx % 576;
    float v = w[(idx / 576) * 192 + (k % 192)];
    unsigned short h = f2bf(v);
    Bp[idx] = (k >= 192 && k < 384) ? f2bf(v - bf2f(h)) : h;
}

// ---------------- proj weights -> bf16 ----------------
__global__ __launch_bounds__(256) void wproj_kernel(
    const float* __restrict__ w, unsigned short* __restrict__ Wp)
{
    int idx = blockIdx.x * 256 + threadIdx.x;   // < 36864
    Wp[idx] = f2bf(w[idx]);
}

// ---------------- Kernel A: split-bf16 MFMA QKV GEMM + grad epilogue ----------------
__global__ __launch_bounds__(256) void qkv_mfma_kernel(
    const unsigned short* __restrict__ x_hi, const unsigned short* __restrict__ x_lo,
    const unsigned short* __restrict__ Bp, const float* __restrict__ bias,
    unsigned short* __restrict__ vT, float* __restrict__ qg, float* __restrict__ kg)
{
    __shared__ unsigned short As[256 * 32];   // [row 256][k 32]
    __shared__ unsigned short Bs[64 * 32];    // [n 64][k 32]

    const int tid  = threadIdx.x;
    const int wave = tid >> 6, lane = tid & 63;
    const int quad = lane >> 4, col = lane & 15;
    const int c0 = blockIdx.x * 64;
    const int m0 = blockIdx.y * 256;

    f32x4 acc[4][4];
#pragma unroll
    for (int mi = 0; mi < 4; ++mi)
#pragma unroll
        for (int ni = 0; ni < 4; ++ni) {
            f32x4 z = {0.f, 0.f, 0.f, 0.f};
            acc[mi][ni] = z;
        }

    const int lr = lane >> 2;
    const int lk = (lane & 3) * 8;

    for (int kk = 0; kk < 18; ++kk) {
        const unsigned short* Asrc = (kk < 12) ? x_hi : x_lo;
        const int ksrc = (kk % 6) * 32;
        __syncthreads();
#pragma unroll
        for (int s = 0; s < 5; ++s) {
            int c = wave * 5 + s;
            if (c < 16) {
                int row = c * 16 + lr;
                const unsigned short* g = Asrc + (size_t)(m0 + row) * 192 + ksrc + lk;
                gl2lds16(g, &As[c * 512]);
            } else {
                int cb = c - 16;
                int row = cb * 16 + lr;
                const unsigned short* g = Bp + (size_t)(c0 + row) * 576 + kk * 32 + lk;
                gl2lds16(g, &Bs[cb * 512]);
            }
        }
        __syncthreads();

        short8 af[4], bfr[4];
#pragma unroll
        for (int mi = 0; mi < 4; ++mi)
            af[mi] = *(const short8*)&As[(wave * 64 + mi * 16 + col) * 32 + quad * 8];
#pragma unroll
        for (int ni = 0; ni < 4; ++ni)
            bfr[ni] = *(const short8*)&Bs[(ni * 16 + col) * 32 + quad * 8];
#pragma unroll
        for (int mi = 0; mi < 4; ++mi)
#pragma unroll
            for (int ni = 0; ni < 4; ++ni)
                acc[mi][ni] = __builtin_amdgcn_mfma_f32_16x16x32_bf16(
                    af[mi], bfr[ni], acc[mi][ni], 0, 0, 0);
    }

#pragma unroll
    for (int ni = 0; ni < 4; ++ni) {
        float bv = bias[c0 + ni * 16 + col];
#pragma unroll
        for (int mi = 0; mi < 4; ++mi)
#pragma unroll
            for (int r = 0; r < 4; ++r)
                acc[mi][ni][r] += bv;
    }

    const int gw = blockIdx.y * 4 + wave;
    const int b = gw >> 8, win = gw & 255;
    const int which = c0 / 192;

    if (which == 2) {
        const int hd0 = c0 - 384;
#pragma unroll
        for (int mi = 0; mi < 4; ++mi)
#pragma unroll
            for (int ni = 0; ni < 4; ++ni) {
                int tok0 = mi * 16 + quad * 4;
                int ch = hd0 + ni * 16 + col;
                ushort4 o = make_ushort4(f2bf(acc[mi][ni][0]), f2bf(acc[mi][ni][1]),
                                         f2bf(acc[mi][ni][2]), f2bf(acc[mi][ni][3]));
                *(ushort4*)(vT + (size_t)(b * 192 + ch) * 16384 + win * 64 + tok0) = o;
            }
    } else {
        float* dst = (which == 0) ? qg : kg;
        const float sc = (which == 0) ? SCALE : 1.0f;
        const int hdb = (which == 0) ? c0 : c0 - 192;
#pragma unroll
        for (int ni = 0; ni < 4; ++ni) {
            float yx[4][4], p3[4];
#pragma unroll
            for (int mi = 0; mi < 4; ++mi) {
#pragma unroll
                for (int r = 0; r < 4; ++r)
                    yx[mi][r] = __shfl_xor(acc[mi][ni][r], 32);
                p3[mi] = __shfl_xor(acc[mi][ni][3], 16);
            }
            float s = 0.f;
#pragma unroll
            for (int mi = 0; mi < 4; ++mi)
#pragma unroll
                for (int r = 0; r < 4; ++r) {
                    float v = acc[mi][ni][r];
                    float gx = (r > 0) ? (v - acc[mi][ni][r - 1])
                                       : ((quad & 1) ? (v - p3[mi]) : v);
                    float gy = (quad >= 2) ? (v - yx[mi][r])
                                           : ((mi > 0) ? (v - yx[mi - 1][r]) : v);
                    s += fabsf(gx) + fabsf(gy);
                }
            s += __shfl_xor(s, 16);
            s += __shfl_xor(s, 32);
            if (lane < 16)
                dst[(size_t)(b * 192 + hdb + ni * 16 + lane) * 256 + win] = s * sc;
        }
    }
}

// ---------------- Kernel B: MFMA rank-1-score softmax attention ----------------
// grid 1536 (one block per (b,ch)), 256 threads = 4 waves; wave w owns query
// windows i in [w*64, w*64+64). C = E[256x256] @ V[256x64], E built in-register.
__global__ __launch_bounds__(256) void attn_mfma_kernel(
    const unsigned short* __restrict__ vT, const float* __restrict__ qg,
    const float* __restrict__ kg, unsigned short* __restrict__ attbuf)
{
    __shared__ unsigned short Vs[64 * 264];   // [tok 64][j 256], stride 264
    __shared__ float kds[256];
    __shared__ float red[256];

    const int g = blockIdx.x;
    const int tid = threadIdx.x;
    const int wave = tid >> 6, lane = tid & 63;
    const int quad = lane >> 4, col = lane & 15;

    float kv = kg[(size_t)g * 256 + tid];
    red[tid] = kv;
    __syncthreads();
    for (int s = 128; s > 0; s >>= 1) {
        if (tid < s) red[tid] = fmaxf(red[tid], red[tid + s]);
        __syncthreads();
    }
    kds[tid] = kv - red[0];                    // <= 0

    // stage V transposed: Vs[tok][j] <- vT[g][j*64+tok]
    const unsigned short* vb = vT + (size_t)g * 16384;
    {
        const int jr = tid >> 3;               // 0..31
        const int tb = (tid & 7) * 8;          // tok base
#pragma unroll
        for (int it = 0; it < 8; ++it) {
            int j = it * 32 + jr;
            uint4 u = *(const uint4*)(vb + (size_t)j * 64 + tb);
            Vs[(tb + 0) * 264 + j] = (unsigned short)(u.x & 0xffffu);
            Vs[(tb + 1) * 264 + j] = (unsigned short)(u.x >> 16);
            Vs[(tb + 2) * 264 + j] = (unsigned short)(u.y & 0xffffu);
            Vs[(tb + 3) * 264 + j] = (unsigned short)(u.y >> 16);
            Vs[(tb + 4) * 264 + j] = (unsigned short)(u.z & 0xffffu);
            Vs[(tb + 5) * 264 + j] = (unsigned short)(u.z >> 16);
            Vs[(tb + 6) * 264 + j] = (unsigned short)(u.w & 0xffffu);
            Vs[(tb + 7) * 264 + j] = (unsigned short)(u.w >> 16);
        }
    }

    float ai[4];
#pragma unroll
    for (int mi = 0; mi < 4; ++mi)
        ai[mi] = qg[(size_t)g * 256 + wave * 64 + mi * 16 + col];

    __syncthreads();

    f32x4 acc[4][4];
#pragma unroll
    for (int mi = 0; mi < 4; ++mi)
#pragma unroll
        for (int ni = 0; ni < 4; ++ni) {
            f32x4 z = {0.f, 0.f, 0.f, 0.f};
            acc[mi][ni] = z;
        }
    float den[4] = {0.f, 0.f, 0.f, 0.f};

    for (int kt = 0; kt < 8; ++kt) {
        const int k0 = kt * 32;
        float4 ka = *(const float4*)&kds[k0 + quad * 8];
        float4 kb = *(const float4*)&kds[k0 + quad * 8 + 4];
        float kv8[8] = {ka.x, ka.y, ka.z, ka.w, kb.x, kb.y, kb.z, kb.w};

        short8 bfr[4];
#pragma unroll
        for (int ni = 0; ni < 4; ++ni)
            bfr[ni] = *(const short8*)&Vs[(ni * 16 + col) * 264 + k0 + quad * 8];

#pragma unroll
        for (int mi = 0; mi < 4; ++mi) {
            short8 ef;
            float dl = 0.f;
#pragma unroll
            for (int j = 0; j < 8; ++j) {
                float e = __expf(ai[mi] * kv8[j]);
                unsigned short h = f2bf(e);
                ef[j] = (short)h;
                dl += bf2f(h);
            }
            den[mi] += dl;
#pragma unroll
            for (int ni = 0; ni < 4; ++ni)
                acc[mi][ni] = __builtin_amdgcn_mfma_f32_16x16x32_bf16(
                    ef, bfr[ni], acc[mi][ni], 0, 0, 0);
        }
    }

#pragma unroll
    for (int mi = 0; mi < 4; ++mi) {
        den[mi] += __shfl_xor(den[mi], 16);
        den[mi] += __shfl_xor(den[mi], 32);
    }
    // lane now has den for row m=col of mtile mi (replicated over quads)

    unsigned short* ob = attbuf + (size_t)g * 16384;
#pragma unroll
    for (int mi = 0; mi < 4; ++mi) {
        float invr[4];
#pragma unroll
        for (int r = 0; r < 4; ++r)
            invr[r] = 1.0f / __shfl(den[mi], quad * 4 + r);
#pragma unroll
        for (int ni = 0; ni < 4; ++ni)
#pragma unroll
            for (int r = 0; r < 4; ++r) {
                int i = wave * 64 + mi * 16 + quad * 4 + r;
                int tok = ni * 16 + col;
                ob[i * 64 + tok] = f2bf(acc[mi][ni][r] * invr[r]);
            }
    }
}

// ---------------- Kernel C: MFMA proj GEMM (C^T = Wp . attbuf^T) ----------------
// grid 2048: block = 64 rows x all 192 couts; wave w -> couts [w*48, w*48+48).
__global__ __launch_bounds__(256) void proj_mfma_kernel(
    const unsigned short* __restrict__ attbuf, const unsigned short* __restrict__ Wp,
    const float* __restrict__ bias, float* __restrict__ out)
{
    __shared__ unsigned short Bs[64 * 40];    // [row 64][ch 32], stride 40
    __shared__ float T[32 * 197];             // transpose half-buffer

    const int tid = threadIdx.x;
    const int wave = tid >> 6, lane = tid & 63;
    const int quad = lane >> 4, col = lane & 15;
    const int rowg0 = blockIdx.x * 64;
    const int b = rowg0 >> 14;
    const int rl0 = rowg0 & 16383;
    const unsigned short* ab = attbuf + (size_t)b * 3145728;

    f32x4 acc[3][4];
#pragma unroll
    for (int mi = 0; mi < 3; ++mi)
#pragma unroll
        for (int ni = 0; ni < 4; ++ni) {
            f32x4 z = {0.f, 0.f, 0.f, 0.f};
            acc[mi][ni] = z;
        }

    const int chl = tid >> 3;            // 0..31
    const int rb = (tid & 7) * 8;        // row base

    for (int kt = 0; kt < 6; ++kt) {
        __syncthreads();
        {
            uint4 u = *(const uint4*)(ab + (size_t)(kt * 32 + chl) * 16384 + rl0 + rb);
            Bs[(rb + 0) * 40 + chl] = (unsigned short)(u.x & 0xffffu);
            Bs[(rb + 1) * 40 + chl] = (unsigned short)(u.x >> 16);
            Bs[(rb + 2) * 40 + chl] = (unsigned short)(u.y & 0xffffu);
            Bs[(rb + 3) * 40 + chl] = (unsigned short)(u.y >> 16);
            Bs[(rb + 4) * 40 + chl] = (unsigned short)(u.z & 0xffffu);
            Bs[(rb + 5) * 40 + chl] = (unsigned short)(u.z >> 16);
            Bs[(rb + 6) * 40 + chl] = (unsigned short)(u.w & 0xffffu);
            Bs[(rb + 7) * 40 + chl] = (unsigned short)(u.w >> 16);
        }
        __syncthreads();

        short8 bfr[4], af[3];
#pragma unroll
        for (int ni = 0; ni < 4; ++ni)
            bfr[ni] = *(const short8*)&Bs[(ni * 16 + col) * 40 + quad * 8];
#pragma unroll
        for (int mi = 0; mi < 3; ++mi)
            af[mi] = *(const short8*)(Wp + (size_t)(wave * 48 + mi * 16 + col) * 192
                                      + kt * 32 + quad * 8);
#pragma unroll
        for (int mi = 0; mi < 3; ++mi)
#pragma unroll
            for (int ni = 0; ni < 4; ++ni)
                acc[mi][ni] = __builtin_amdgcn_mfma_f32_16x16x32_bf16(
                    af[mi], bfr[ni], acc[mi][ni], 0, 0, 0);
    }

    float br[3][4];
#pragma unroll
    for (int mi = 0; mi < 3; ++mi)
#pragma unroll
        for (int r = 0; r < 4; ++r)
            br[mi][r] = bias[wave * 48 + mi * 16 + quad * 4 + r];

    // epilogue in two 32-row halves: regs (C^T) -> T[row][cout] -> coalesced out
#pragma unroll
    for (int h = 0; h < 2; ++h) {
        __syncthreads();
#pragma unroll
        for (int nh = 0; nh < 2; ++nh) {
            int ni = h * 2 + nh;
#pragma unroll
            for (int mi = 0; mi < 3; ++mi)
#pragma unroll
                for (int r = 0; r < 4; ++r)
                    T[(nh * 16 + col) * 197 + wave * 48 + mi * 16 + quad * 4 + r] =
                        acc[mi][ni][r] + br[mi][r];
        }
        __syncthreads();
        {
            int row = tid >> 3;              // 0..31
            int ck = (tid & 7) * 24;         // cout chunk
            float* op = out + (size_t)(rowg0 + h * 32 + row) * 192 + ck;
#pragma unroll
            for (int q4 = 0; q4 < 6; ++q4) {
                float4 o = make_float4(T[row * 197 + ck + q4 * 4 + 0],
                                       T[row * 197 + ck + q4 * 4 + 1],
                                       T[row * 197 + ck + q4 * 4 + 2],
                                       T[row * 197 + ck + q4 * 4 + 3]);
                *(float4*)(op + q4 * 4) = o;
            }
        }
    }
}

extern "C" void kernel_launch(void* const* d_in, const int* in_sizes, int n_in,
                              void* d_out, int out_size, void* d_ws, size_t ws_size,
                              hipStream_t stream) {
    const float* x      = (const float*)d_in[0];
    const float* qkv_w  = (const float*)d_in[1];
    const float* qkv_b  = (const float*)d_in[2];
    const float* proj_w = (const float*)d_in[3];
    const float* proj_b = (const float*)d_in[4];
    float* out = (float*)d_out;

    unsigned short* base16 = (unsigned short*)d_ws;
    unsigned short* vT16    = base16;                     // 25165824 u16
    unsigned short* x_hi    = base16 + 25165824;          // 25165824 u16
    unsigned short* x_lo    = base16 + 50331648;          // 25165824 u16
    unsigned short* attbuf  = x_hi;                       // alias (x_hi dead after qkv)
    float* qg = (float*)(base16 + 75497472);              // 393216 f32
    float* kg = qg + 393216;                              // 393216 f32
    unsigned short* Bp = (unsigned short*)(kg + 393216);  // 331776 u16
    unsigned short* Wp = Bp + 331776;                     // 36864 u16

    split_kernel<<<12288, 256, 0, stream>>>(x, x_hi, x_lo);
    bsplit_kernel<<<1296, 256, 0, stream>>>(qkv_w, Bp);
    wproj_kernel<<<144, 256, 0, stream>>>(proj_w, Wp);
    qkv_mfma_kernel<<<dim3(9, 512), 256, 0, stream>>>(x_hi, x_lo, Bp, qkv_b, vT16, qg, kg);
    attn_mfma_kernel<<<dim3(1536), 256, 0, stream>>>(vT16, qg, kg, attbuf);
    proj_mfma_kernel<<<dim3(2048), 256, 0, stream>>>(attbuf, proj_w == nullptr ? Wp : Wp, proj_b, out);
}

// Round 4
// 364.515 us; speedup vs baseline: 2.3708x; 1.3040x over previous
//
#include <hip/hip_runtime.h>
#include <cstddef>

// Shapes: B=8, NWIN=256, NTOK=64, DIM=192, HEADS=6, d=32, 3C=576
// ws layout (u16 units from base):
//   vT16    [0,        25165824)  bf16 v transposed [(b*192+ch)][win*64+tok]
//   attbuf  [25165824, 50331648)  bf16 softmax@V output [(b*192+ch)][i*64+tok]
//   qg,kg   f32 at u16 offset 50331648 (2 x 393216 f32)
//   Wh [576][192] bf16, Wl [384][192] bf16 (qkv weight hi/lo), Wp [192][192] bf16

#define SCALE 0.17677669529663687f   // 1/sqrt(32)

typedef __attribute__((ext_vector_type(8))) short short8;
typedef __attribute__((ext_vector_type(4))) float f32x4;

__device__ __forceinline__ unsigned short f2bf(float f) {
    unsigned u = __float_as_uint(f);
    u += 0x7fffu + ((u >> 16) & 1u);
    return (unsigned short)(u >> 16);
}
__device__ __forceinline__ float bf2f(unsigned int h) {
    return __uint_as_float(h << 16);
}
__device__ __forceinline__ unsigned pack2(unsigned short a, unsigned short b) {
    return (unsigned)a | ((unsigned)b << 16);
}

// ---------------- qkv weights -> bf16 hi (all 576 rows) + lo (first 384 rows) ----------------
__global__ __launch_bounds__(256) void wsplit_kernel(
    const float* __restrict__ w, unsigned short* __restrict__ Wh,
    unsigned short* __restrict__ Wl)
{
    int idx = blockIdx.x * 256 + threadIdx.x;   // < 110592 = 576*192
    float v = w[idx];
    unsigned short h = f2bf(v);
    Wh[idx] = h;
    if (idx < 73728) Wl[idx] = f2bf(v - bf2f(h));   // rows 0..383 (q,k)
}

// ---------------- proj weights -> bf16 ----------------
__global__ __launch_bounds__(256) void wproj_kernel(
    const float* __restrict__ w, unsigned short* __restrict__ Wp)
{
    int idx = blockIdx.x * 256 + threadIdx.x;   // < 36864
    Wp[idx] = f2bf(w[idx]);
}

// ---------------- Kernel A: fused split + N-resident QKV GEMM + grad epilogue ----------------
// grid 1024, block 512 = 8 waves. Block = 128 rows (2 windows); waves 0-3 ->
// rows 0-63 (window 0), waves 4-7 -> rows 64-127 (window 1). Wave sweeps
// ntiles n = (wave&3) + 4*s, s=0..8 (N=576 resident in acc: 36 tiles/lane=144 VGPR).
// K-loop: 6 chunks of 32; x read fp32 ONCE, hi/lo split in-register; W staged
// hi+lo per chunk; V columns (n>=24) use hi*hi only.
__global__ __launch_bounds__(512, 2) void qkv_fused_kernel(
    const float* __restrict__ x, const unsigned short* __restrict__ Wh,
    const unsigned short* __restrict__ Wl, const float* __restrict__ bias,
    unsigned short* __restrict__ vT, float* __restrict__ qg, float* __restrict__ kg)
{
    __shared__ unsigned short As_h[128 * 40];   // [row][k32], stride 40 (pad)
    __shared__ unsigned short As_l[128 * 40];
    __shared__ unsigned short Bs_h[576 * 40];
    __shared__ unsigned short Bs_l[384 * 40];

    const int tid = threadIdx.x;
    const int wave = tid >> 6, lane = tid & 63;
    const int quad = lane >> 4, col = lane & 15;
    const int wq = wave & 3, wofs = (wave >> 2) * 64;
    const int m0 = blockIdx.x * 128;

    // staging assignments
    const int arow = tid >> 2;              // 0..127
    const int apart = (tid & 3) * 8;        // {0,8,16,24} u16/f32 offset
    const float* xp = x + (size_t)(m0 + arow) * 192 + apart;

    f32x4 acc[9][4];
#pragma unroll
    for (int s = 0; s < 9; ++s)
#pragma unroll
        for (int mi = 0; mi < 4; ++mi) {
            f32x4 z = {0.f, 0.f, 0.f, 0.f};
            acc[s][mi] = z;
        }

    float4 pa0, pa1;
    uint4 pbh[5], pbl[3];

    auto load_chunk = [&](int kk) {
        const int k0 = kk * 32;
        pa0 = *(const float4*)(xp + k0);
        pa1 = *(const float4*)(xp + k0 + 4);
#pragma unroll
        for (int i = 0; i < 5; ++i) {
            int idx = tid + i * 512;
            if (idx < 2304)
                pbh[i] = *(const uint4*)(Wh + (size_t)(idx >> 2) * 192 + k0 + (idx & 3) * 8);
        }
#pragma unroll
        for (int i = 0; i < 3; ++i) {
            int idx = tid + i * 512;
            pbl[i] = *(const uint4*)(Wl + (size_t)(idx >> 2) * 192 + k0 + (idx & 3) * 8);
        }
    };

    auto write_chunk = [&]() {
        float v[8] = {pa0.x, pa0.y, pa0.z, pa0.w, pa1.x, pa1.y, pa1.z, pa1.w};
        unsigned short h[8], l[8];
#pragma unroll
        for (int i = 0; i < 8; ++i) {
            h[i] = f2bf(v[i]);
            l[i] = f2bf(v[i] - bf2f(h[i]));
        }
        uint4 H = make_uint4(pack2(h[0], h[1]), pack2(h[2], h[3]),
                             pack2(h[4], h[5]), pack2(h[6], h[7]));
        uint4 L = make_uint4(pack2(l[0], l[1]), pack2(l[2], l[3]),
                             pack2(l[4], l[5]), pack2(l[6], l[7]));
        *(uint4*)&As_h[arow * 40 + apart] = H;
        *(uint4*)&As_l[arow * 40 + apart] = L;
#pragma unroll
        for (int i = 0; i < 5; ++i) {
            int idx = tid + i * 512;
            if (idx < 2304)
                *(uint4*)&Bs_h[(idx >> 2) * 40 + (idx & 3) * 8] = pbh[i];
        }
#pragma unroll
        for (int i = 0; i < 3; ++i) {
            int idx = tid + i * 512;
            *(uint4*)&Bs_l[(idx >> 2) * 40 + (idx & 3) * 8] = pbl[i];
        }
    };

    load_chunk(0);
    for (int kk = 0; kk < 6; ++kk) {
        __syncthreads();
        write_chunk();
        __syncthreads();
        if (kk < 5) load_chunk(kk + 1);

        short8 ah[4], al[4];
#pragma unroll
        for (int mi = 0; mi < 4; ++mi) {
            int r = wofs + mi * 16 + col;
            ah[mi] = *(const short8*)&As_h[r * 40 + quad * 8];
            al[mi] = *(const short8*)&As_l[r * 40 + quad * 8];
        }
#pragma unroll
        for (int s = 0; s < 9; ++s) {
            const int nr = (wq + s * 4) * 16 + col;
            short8 bh = *(const short8*)&Bs_h[nr * 40 + quad * 8];
            if (s < 6) {
                short8 bl = *(const short8*)&Bs_l[nr * 40 + quad * 8];
#pragma unroll
                for (int mi = 0; mi < 4; ++mi) {
                    acc[s][mi] = __builtin_amdgcn_mfma_f32_16x16x32_bf16(al[mi], bh, acc[s][mi], 0, 0, 0);
                    acc[s][mi] = __builtin_amdgcn_mfma_f32_16x16x32_bf16(ah[mi], bl, acc[s][mi], 0, 0, 0);
                    acc[s][mi] = __builtin_amdgcn_mfma_f32_16x16x32_bf16(ah[mi], bh, acc[s][mi], 0, 0, 0);
                }
            } else {
#pragma unroll
                for (int mi = 0; mi < 4; ++mi)
                    acc[s][mi] = __builtin_amdgcn_mfma_f32_16x16x32_bf16(ah[mi], bh, acc[s][mi], 0, 0, 0);
            }
        }
    }

    // bias (before grads: zero-pad boundary terms keep the bias)
#pragma unroll
    for (int s = 0; s < 9; ++s) {
        float bv = bias[(wq + s * 4) * 16 + col];
#pragma unroll
        for (int mi = 0; mi < 4; ++mi)
#pragma unroll
            for (int r = 0; r < 4; ++r)
                acc[s][mi][r] += bv;
    }

    const int gw = blockIdx.x * 2 + (wave >> 2);     // global window of this wave
    const int b = gw >> 8, win = gw & 255;

    // s = 0..2 -> q (ntiles 0..11), 3..5 -> k (12..23), 6..8 -> v (24..35)
#pragma unroll
    for (int s = 0; s < 6; ++s) {
        const int n = wq + s * 4;
        float yx[4][4], p3[4];
#pragma unroll
        for (int mi = 0; mi < 4; ++mi) {
#pragma unroll
            for (int r = 0; r < 4; ++r)
                yx[mi][r] = __shfl_xor(acc[s][mi][r], 32);
            p3[mi] = __shfl_xor(acc[s][mi][3], 16);
        }
        float sum = 0.f;
#pragma unroll
        for (int mi = 0; mi < 4; ++mi)
#pragma unroll
            for (int r = 0; r < 4; ++r) {
                float v = acc[s][mi][r];
                float gx = (r > 0) ? (v - acc[s][mi][r - 1])
                                   : ((quad & 1) ? (v - p3[mi]) : v);
                float gy = (quad >= 2) ? (v - yx[mi][r])
                                       : ((mi > 0) ? (v - yx[mi - 1][r]) : v);
                sum += fabsf(gx) + fabsf(gy);
            }
        sum += __shfl_xor(sum, 16);
        sum += __shfl_xor(sum, 32);
        float* dst = (s < 3) ? qg : kg;
        const int chb = ((s < 3) ? n : n - 12) * 16;
        const float sc = (s < 3) ? SCALE : 1.0f;
        if (lane < 16)
            dst[(size_t)(b * 192 + chb + lane) * 256 + win] = sum * sc;
    }
#pragma unroll
    for (int s = 6; s < 9; ++s) {
        const int ch = (wq + s * 4 - 24) * 16 + col;
#pragma unroll
        for (int mi = 0; mi < 4; ++mi) {
            int tok0 = mi * 16 + quad * 4;
            ushort4 o = make_ushort4(f2bf(acc[s][mi][0]), f2bf(acc[s][mi][1]),
                                     f2bf(acc[s][mi][2]), f2bf(acc[s][mi][3]));
            *(ushort4*)(vT + (size_t)(b * 192 + ch) * 16384 + win * 64 + tok0) = o;
        }
    }
}

// ---------------- Kernel B: MFMA rank-1-score softmax attention ----------------
// grid 1536 (one block per (b,ch)), 256 threads = 4 waves; wave w owns query
// windows i in [w*64, w*64+64). C = E[256x256] @ V[256x64], E built in-register.
__global__ __launch_bounds__(256) void attn_mfma_kernel(
    const unsigned short* __restrict__ vT, const float* __restrict__ qg,
    const float* __restrict__ kg, unsigned short* __restrict__ attbuf)
{
    __shared__ unsigned short Vs[64 * 264];   // [tok 64][j 256], stride 264
    __shared__ float kds[256];
    __shared__ float red[256];

    const int g = blockIdx.x;
    const int tid = threadIdx.x;
    const int wave = tid >> 6, lane = tid & 63;
    const int quad = lane >> 4, col = lane & 15;

    float kv = kg[(size_t)g * 256 + tid];
    red[tid] = kv;
    __syncthreads();
    for (int s = 128; s > 0; s >>= 1) {
        if (tid < s) red[tid] = fmaxf(red[tid], red[tid + s]);
        __syncthreads();
    }
    kds[tid] = kv - red[0];                    // <= 0

    // stage V transposed: Vs[tok][j] <- vT[g][j*64+tok]
    const unsigned short* vb = vT + (size_t)g * 16384;
    {
        const int jr = tid >> 3;               // 0..31
        const int tb = (tid & 7) * 8;          // tok base
#pragma unroll
        for (int it = 0; it < 8; ++it) {
            int j = it * 32 + jr;
            uint4 u = *(const uint4*)(vb + (size_t)j * 64 + tb);
            Vs[(tb + 0) * 264 + j] = (unsigned short)(u.x & 0xffffu);
            Vs[(tb + 1) * 264 + j] = (unsigned short)(u.x >> 16);
            Vs[(tb + 2) * 264 + j] = (unsigned short)(u.y & 0xffffu);
            Vs[(tb + 3) * 264 + j] = (unsigned short)(u.y >> 16);
            Vs[(tb + 4) * 264 + j] = (unsigned short)(u.z & 0xffffu);
            Vs[(tb + 5) * 264 + j] = (unsigned short)(u.z >> 16);
            Vs[(tb + 6) * 264 + j] = (unsigned short)(u.w & 0xffffu);
            Vs[(tb + 7) * 264 + j] = (unsigned short)(u.w >> 16);
        }
    }

    float ai[4];
#pragma unroll
    for (int mi = 0; mi < 4; ++mi)
        ai[mi] = qg[(size_t)g * 256 + wave * 64 + mi * 16 + col];

    __syncthreads();

    f32x4 acc[4][4];
#pragma unroll
    for (int mi = 0; mi < 4; ++mi)
#pragma unroll
        for (int ni = 0; ni < 4; ++ni) {
            f32x4 z = {0.f, 0.f, 0.f, 0.f};
            acc[mi][ni] = z;
        }
    float den[4] = {0.f, 0.f, 0.f, 0.f};

    for (int kt = 0; kt < 8; ++kt) {
        const int k0 = kt * 32;
        float4 ka = *(const float4*)&kds[k0 + quad * 8];
        float4 kb = *(const float4*)&kds[k0 + quad * 8 + 4];
        float kv8[8] = {ka.x, ka.y, ka.z, ka.w, kb.x, kb.y, kb.z, kb.w};

        short8 bfr[4];
#pragma unroll
        for (int ni = 0; ni < 4; ++ni)
            bfr[ni] = *(const short8*)&Vs[(ni * 16 + col) * 264 + k0 + quad * 8];

#pragma unroll
        for (int mi = 0; mi < 4; ++mi) {
            short8 ef;
            float dl = 0.f;
#pragma unroll
            for (int j = 0; j < 8; ++j) {
                float e = __expf(ai[mi] * kv8[j]);
                unsigned short h = f2bf(e);
                ef[j] = (short)h;
                dl += bf2f(h);
            }
            den[mi] += dl;
#pragma unroll
            for (int ni = 0; ni < 4; ++ni)
                acc[mi][ni] = __builtin_amdgcn_mfma_f32_16x16x32_bf16(
                    ef, bfr[ni], acc[mi][ni], 0, 0, 0);
        }
    }

#pragma unroll
    for (int mi = 0; mi < 4; ++mi) {
        den[mi] += __shfl_xor(den[mi], 16);
        den[mi] += __shfl_xor(den[mi], 32);
    }

    unsigned short* ob = attbuf + (size_t)g * 16384;
#pragma unroll
    for (int mi = 0; mi < 4; ++mi) {
        float invr[4];
#pragma unroll
        for (int r = 0; r < 4; ++r)
            invr[r] = 1.0f / __shfl(den[mi], quad * 4 + r);
#pragma unroll
        for (int ni = 0; ni < 4; ++ni)
#pragma unroll
            for (int r = 0; r < 4; ++r) {
                int i = wave * 64 + mi * 16 + quad * 4 + r;
                int tok = ni * 16 + col;
                ob[i * 64 + tok] = f2bf(acc[mi][ni][r] * invr[r]);
            }
    }
}

// ---------------- Kernel C: MFMA proj GEMM (C^T = Wp . attbuf^T) ----------------
__global__ __launch_bounds__(256) void proj_mfma_kernel(
    const unsigned short* __restrict__ attbuf, const unsigned short* __restrict__ Wp,
    const float* __restrict__ bias, float* __restrict__ out)
{
    __shared__ unsigned short Bs[64 * 40];    // [row 64][ch 32], stride 40
    __shared__ float T[32 * 197];             // transpose half-buffer

    const int tid = threadIdx.x;
    const int wave = tid >> 6, lane = tid & 63;
    const int quad = lane >> 4, col = lane & 15;
    const int rowg0 = blockIdx.x * 64;
    const int b = rowg0 >> 14;
    const int rl0 = rowg0 & 16383;
    const unsigned short* ab = attbuf + (size_t)b * 3145728;

    f32x4 acc[3][4];
#pragma unroll
    for (int mi = 0; mi < 3; ++mi)
#pragma unroll
        for (int ni = 0; ni < 4; ++ni) {
            f32x4 z = {0.f, 0.f, 0.f, 0.f};
            acc[mi][ni] = z;
        }

    const int chl = tid >> 3;            // 0..31
    const int rb = (tid & 7) * 8;        // row base

    for (int kt = 0; kt < 6; ++kt) {
        __syncthreads();
        {
            uint4 u = *(const uint4*)(ab + (size_t)(kt * 32 + chl) * 16384 + rl0 + rb);
            Bs[(rb + 0) * 40 + chl] = (unsigned short)(u.x & 0xffffu);
            Bs[(rb + 1) * 40 + chl] = (unsigned short)(u.x >> 16);
            Bs[(rb + 2) * 40 + chl] = (unsigned short)(u.y & 0xffffu);
            Bs[(rb + 3) * 40 + chl] = (unsigned short)(u.y >> 16);
            Bs[(rb + 4) * 40 + chl] = (unsigned short)(u.z & 0xffffu);
            Bs[(rb + 5) * 40 + chl] = (unsigned short)(u.z >> 16);
            Bs[(rb + 6) * 40 + chl] = (unsigned short)(u.w & 0xffffu);
            Bs[(rb + 7) * 40 + chl] = (unsigned short)(u.w >> 16);
        }
        __syncthreads();

        short8 bfr[4], af[3];
#pragma unroll
        for (int ni = 0; ni < 4; ++ni)
            bfr[ni] = *(const short8*)&Bs[(ni * 16 + col) * 40 + quad * 8];
#pragma unroll
        for (int mi = 0; mi < 3; ++mi)
            af[mi] = *(const short8*)(Wp + (size_t)(wave * 48 + mi * 16 + col) * 192
                                      + kt * 32 + quad * 8);
#pragma unroll
        for (int mi = 0; mi < 3; ++mi)
#pragma unroll
            for (int ni = 0; ni < 4; ++ni)
                acc[mi][ni] = __builtin_amdgcn_mfma_f32_16x16x32_bf16(
                    af[mi], bfr[ni], acc[mi][ni], 0, 0, 0);
    }

    float br[3][4];
#pragma unroll
    for (int mi = 0; mi < 3; ++mi)
#pragma unroll
        for (int r = 0; r < 4; ++r)
            br[mi][r] = bias[wave * 48 + mi * 16 + quad * 4 + r];

#pragma unroll
    for (int h = 0; h < 2; ++h) {
        __syncthreads();
#pragma unroll
        for (int nh = 0; nh < 2; ++nh) {
            int ni = h * 2 + nh;
#pragma unroll
            for (int mi = 0; mi < 3; ++mi)
#pragma unroll
                for (int r = 0; r < 4; ++r)
                    T[(nh * 16 + col) * 197 + wave * 48 + mi * 16 + quad * 4 + r] =
                        acc[mi][ni][r] + br[mi][r];
        }
        __syncthreads();
        {
            int row = tid >> 3;              // 0..31
            int ck = (tid & 7) * 24;         // cout chunk
            float* op = out + (size_t)(rowg0 + h * 32 + row) * 192 + ck;
#pragma unroll
            for (int q4 = 0; q4 < 6; ++q4) {
                float4 o = make_float4(T[row * 197 + ck + q4 * 4 + 0],
                                       T[row * 197 + ck + q4 * 4 + 1],
                                       T[row * 197 + ck + q4 * 4 + 2],
                                       T[row * 197 + ck + q4 * 4 + 3]);
                *(float4*)(op + q4 * 4) = o;
            }
        }
    }
}

extern "C" void kernel_launch(void* const* d_in, const int* in_sizes, int n_in,
                              void* d_out, int out_size, void* d_ws, size_t ws_size,
                              hipStream_t stream) {
    const float* x      = (const float*)d_in[0];
    const float* qkv_w  = (const float*)d_in[1];
    const float* qkv_b  = (const float*)d_in[2];
    const float* proj_w = (const float*)d_in[3];
    const float* proj_b = (const float*)d_in[4];
    float* out = (float*)d_out;

    unsigned short* base16 = (unsigned short*)d_ws;
    unsigned short* vT16   = base16;                      // 25165824 u16
    unsigned short* attbuf = base16 + 25165824;           // 25165824 u16
    float* qg = (float*)(base16 + 50331648);              // 393216 f32
    float* kg = qg + 393216;                              // 393216 f32
    unsigned short* Wh = (unsigned short*)(kg + 393216);  // 110592 u16
    unsigned short* Wl = Wh + 110592;                     // 73728 u16
    unsigned short* Wp = Wl + 73728;                      // 36864 u16

    wsplit_kernel<<<432, 256, 0, stream>>>(qkv_w, Wh, Wl);
    wproj_kernel<<<144, 256, 0, stream>>>(proj_w, Wp);
    qkv_fused_kernel<<<1024, 512, 0, stream>>>(x, Wh, Wl, qkv_b, vT16, qg, kg);
    attn_mfma_kernel<<<1536, 256, 0, stream>>>(vT16, qg, kg, attbuf);
    proj_mfma_kernel<<<2048, 256, 0, stream>>>(attbuf, Wp, proj_b, out);
}